// Round 18
// baseline (155.699 us; speedup 1.0000x reference)
//
#include <hip/hip_runtime.h>
#include <math.h>

#define BATCH 64
#define NOBJ 16
#define NPRIOR 8732
#define NC 91
#define IMG 300.0f
#define GPB 1092                   // 8-row groups per batch (k_ce)
#define NGROUP (GPB * BATCH)       // 69888
#define CE_GRID 6144               // one-wave blocks
#define GBINS 2048                 // histogram bins: bin = min(2047, v*128)
#define HB 16                      // hist blocks (= private copies) per batch
#define HCHUNK 546                 // priors per hist block (16*546 >= 8732)

// ---------------------------------------------------------------- k_match
__global__ __launch_bounds__(1024) void k_match(
    const float* __restrict__ loc_data,
    const float* __restrict__ gt_boxes,
    const int*   __restrict__ gt_labels,
    const float* __restrict__ priors,
    int*   __restrict__ conf_t,
    int*   __restrict__ num_pos_b,
    float* __restrict__ ll_b)
{
    __shared__ float s_ov[NPRIOR];
    __shared__ unsigned char s_idx[NPRIOR];
    __shared__ float bx0[NOBJ], by0[NOBJ], bx1[NOBJ], by1[NOBJ], barea[NOBJ];
    __shared__ int   blab[NOBJ];
    __shared__ float rv[NOBJ][16];
    __shared__ int   ri[NOBJ][16];
    __shared__ int   bpi[NOBJ];
    __shared__ float red_f[16];
    __shared__ int   red_i[16];

    const int b    = blockIdx.x;
    const int tid  = threadIdx.x;
    const int lane = tid & 63;
    const int wave = tid >> 6;

    if (tid < NOBJ) {
        float4 g = ((const float4*)gt_boxes)[(size_t)b * NOBJ + tid];
        float x0 = g.x * (1.0f / IMG), y0 = g.y * (1.0f / IMG);
        float x1 = g.z * (1.0f / IMG), y1 = g.w * (1.0f / IMG);
        bx0[tid] = x0; by0[tid] = y0; bx1[tid] = x1; by1[tid] = y1;
        barea[tid] = (x1 - x0) * (y1 - y0);
        blab[tid] = gt_labels[b * NOBJ + tid];
    }
    __syncthreads();

    float bv[NOBJ];
    int   bi[NOBJ];
#pragma unroll
    for (int j = 0; j < NOBJ; j++) { bv[j] = -1.0f; bi[j] = 0x7fffffff; }

    for (int p = tid; p < NPRIOR; p += 1024) {
        float4 pr = ((const float4*)priors)[p];
        float cx = pr.x, cy = pr.y, w = pr.z, h = pr.w;
        float px0 = cx - 0.5f * w, py0 = cy - 0.5f * h;
        float px1 = cx + 0.5f * w, py1 = cy + 0.5f * h;
        float pa = w * h;
        float maxv = -1.0f; int maxj = 0;
#pragma unroll
        for (int j = 0; j < NOBJ; j++) {
            float ltx = fmaxf(bx0[j], px0), lty = fmaxf(by0[j], py0);
            float rbx = fminf(bx1[j], px1), rby = fminf(by1[j], py1);
            float iw = fmaxf(rbx - ltx, 0.0f), ih = fmaxf(rby - lty, 0.0f);
            float inter = iw * ih;
            float iou = inter / (barea[j] + pa - inter);
            if (iou > maxv) { maxv = iou; maxj = j; }
            if (iou > bv[j]) { bv[j] = iou; bi[j] = p; }
        }
        s_ov[p]  = maxv;
        s_idx[p] = (unsigned char)maxj;
    }

#pragma unroll
    for (int j = 0; j < NOBJ; j++) {
        float v = bv[j]; int ix = bi[j];
        for (int off = 32; off; off >>= 1) {
            float v2 = __shfl_xor(v, off);
            int   i2 = __shfl_xor(ix, off);
            if (v2 > v || (v2 == v && i2 < ix)) { v = v2; ix = i2; }
        }
        if (lane == 0) { rv[j][wave] = v; ri[j][wave] = ix; }
    }
    __syncthreads();
    if (tid < NOBJ) {
        int j = tid;
        float v = rv[j][0]; int ix = ri[j][0];
        for (int w2 = 1; w2 < 16; w2++) {
            float v2 = rv[j][w2]; int i2 = ri[j][w2];
            if (v2 > v || (v2 == v && i2 < ix)) { v = v2; ix = i2; }
        }
        bpi[j] = ix;
    }
    __syncthreads();
    if (tid == 0) {
        for (int j = 0; j < NOBJ; j++) s_ov[bpi[j]] = 2.0f;
        for (int j = 0; j < NOBJ; j++) s_idx[bpi[j]] = (unsigned char)j;
    }
    __syncthreads();

    int np_local = 0;
    float ll_local = 0.0f;
    for (int p = tid; p < NPRIOR; p += 1024) {
        float ov = s_ov[p];
        int ti = (int)s_idx[p];
        int conf = (ov < 0.5f) ? 0 : blab[ti];
        conf_t[(size_t)b * NPRIOR + p] = conf;
        if (conf > 0) {
            np_local++;
            float4 pr = ((const float4*)priors)[p];
            float cx = pr.x, cy = pr.y, w = pr.z, h = pr.w;
            float mx0 = bx0[ti], my0 = by0[ti], mx1 = bx1[ti], my1 = by1[ti];
            float g0 = ((mx0 + mx1) * 0.5f - cx) / (0.1f * w);
            float g1 = ((my0 + my1) * 0.5f - cy) / (0.1f * h);
            float g2 = logf((mx1 - mx0) / w) * 5.0f;
            float g3 = logf((my1 - my0) / h) * 5.0f;
            float4 lv = ((const float4*)loc_data)[(size_t)b * NPRIOR + p];
            float d0 = lv.x - g0, d1 = lv.y - g1, d2 = lv.z - g2, d3 = lv.w - g3;
            float a0 = fabsf(d0), a1 = fabsf(d1), a2 = fabsf(d2), a3 = fabsf(d3);
            ll_local += (a0 < 1.f ? 0.5f * d0 * d0 : a0 - 0.5f)
                      + (a1 < 1.f ? 0.5f * d1 * d1 : a1 - 0.5f)
                      + (a2 < 1.f ? 0.5f * d2 * d2 : a2 - 0.5f)
                      + (a3 < 1.f ? 0.5f * d3 * d3 : a3 - 0.5f);
        }
    }
    for (int off = 32; off; off >>= 1) {
        ll_local += __shfl_xor(ll_local, off);
        np_local += __shfl_xor(np_local, off);
    }
    if (lane == 0) { red_f[wave] = ll_local; red_i[wave] = np_local; }
    __syncthreads();
    if (tid == 0) {
        float ll = 0.0f; int np = 0;
        for (int w2 = 0; w2 < 16; w2++) { ll += red_f[w2]; np += red_i[w2]; }
        num_pos_b[b] = np;
        ll_b[b] = ll;
    }
}

// ---------------------------------------------------------------- k_ce
// One-wave persistent blocks, zero barriers, depth-2 register pipeline.

#define CE_ISSUE(gg, R0, R1, R2, NF)                                           \
    {   int b_ = (gg) / GPB, ci_ = (gg) - b_ * GPB;                            \
        int p0_ = ci_ * 8;                                                     \
        int rows_ = min(8, NPRIOR - p0_);                                      \
        NF = (rows_ * NC) >> 2;                                                \
        const float4* s_ = (const float4*)(conf_data + ((size_t)b_ * NPRIOR + p0_) * NC); \
        R0 = s_[tid];                                                          \
        if (tid + 64  < NF) R1 = s_[tid + 64];                                 \
        if (tid + 128 < NF) R2 = s_[tid + 128]; }

#define CT_LOAD(gg)                                                            \
    ( conf_t[(size_t)((gg) / GPB) * NPRIOR + ((gg) - ((gg) / GPB) * GPB) * 8 + (tid >> 3)] )

#define CE_WRITE(BUF, R0, R1, R2, NF)                                          \
    {   float4* d_ = (float4*)sbuf[BUF];                                       \
        d_[tid] = R0;                                                          \
        if (tid + 64  < NF) d_[tid + 64]  = R1;                                \
        if (tid + 128 < NF) d_[tid + 128] = R2; }

#define CE_COMPUTE(gg, BUF, TG)                                                \
    {   int b_ = (gg) / GPB, ci_ = (gg) - b_ * GPB;                            \
        int p0_ = ci_ * 8;                                                     \
        int rows_ = min(8, NPRIOR - p0_);                                      \
        int rr_ = tid >> 3, q_ = tid & 7;                                      \
        if (rr_ < rows_) {                                                     \
            const float* row_ = sbuf[BUF] + rr_ * NC;                          \
            float s_ = 0.0f;                                                   \
            _Pragma("unroll")                                                  \
            for (int i_ = q_; i_ < NC; i_ += 8) s_ += __expf(row_[i_]);        \
            s_ += __shfl_xor(s_, 1);                                           \
            s_ += __shfl_xor(s_, 2);                                           \
            s_ += __shfl_xor(s_, 4);                                           \
            if (q_ == 0) {                                                     \
                size_t o_ = (size_t)b_ * NPRIOR + p0_ + rr_;                   \
                int tgt_ = TG;                                                 \
                float ce_ = __logf(s_) - row_[tgt_];                           \
                if (tgt_ > 0) { pos_acc += ce_; mine[o_] = 0.0f; }             \
                else          { mine[o_] = fmaxf(ce_, 0.0f); }                 \
            } } }

__global__ __launch_bounds__(64) void k_ce(
    const float* __restrict__ conf_data,
    const int*   __restrict__ conf_t,
    float* __restrict__ mine,
    float* __restrict__ lc_part)
{
    __shared__ float sbuf[2][8 * NC];
    const int tid = threadIdx.x;
    const int G = CE_GRID;

    float4 a0, a1, a2, b0, b1, b2;
    int nfA = 0, nfB = 0;
    float pos_acc = 0.0f;

    int g = blockIdx.x;
    CE_ISSUE(g, a0, a1, a2, nfA);
    int tcur = CT_LOAD(g);
    if (g + G < NGROUP) CE_ISSUE(g + G, b0, b1, b2, nfB);
    CE_WRITE(0, a0, a1, a2, nfA);

    for (; g < NGROUP; g += 2 * G) {
        int tnext = (g + G < NGROUP) ? CT_LOAD(g + G) : 0;
        if (g + 2 * G < NGROUP) CE_ISSUE(g + 2 * G, a0, a1, a2, nfA);
        CE_COMPUTE(g, 0, tcur);
        if (g + G < NGROUP) {
            CE_WRITE(1, b0, b1, b2, nfB);
            int tn2 = (g + 2 * G < NGROUP) ? CT_LOAD(g + 2 * G) : 0;
            if (g + 3 * G < NGROUP) CE_ISSUE(g + 3 * G, b0, b1, b2, nfB);
            CE_COMPUTE(g + G, 1, tnext);
            if (g + 2 * G < NGROUP) CE_WRITE(0, a0, a1, a2, nfA);
            tcur = tn2;
        }
    }

    for (int off = 32; off; off >>= 1) pos_acc += __shfl_xor(pos_acc, off);
    if (tid == 0) lc_part[blockIdx.x] = pos_acc;
}

// ---------------------------------------------------------------- k_hist
// 16 blocks x 256 thr per batch: private LDS histogram (count+sum), plain
// coalesced stores of the private copy to ghc/gsc. No global atomics.
// Overwrite-idempotent: pure function of mine -> safe to launch 3x.
__global__ __launch_bounds__(256) void k_hist(
    const float* __restrict__ mine,
    int*   __restrict__ ghc,          // [B][HB][GBINS]
    float* __restrict__ gsc)          // [B][HB][GBINS]
{
    __shared__ int   lh[GBINS];
    __shared__ float ls[GBINS];

    const int b  = blockIdx.y;
    const int ci = blockIdx.x;
    const int tid = threadIdx.x;
    const int i0 = ci * HCHUNK;
    const int iend = min(i0 + HCHUNK, NPRIOR);

#pragma unroll
    for (int j = 0; j < GBINS / 256; j++) {
        lh[tid + j * 256] = 0;
        ls[tid + j * 256] = 0.0f;
    }
    __syncthreads();

    for (int i = i0 + tid; i < iend; i += 256) {
        float v = mine[(size_t)b * NPRIOR + i];
        int bin = min((int)(v * 128.0f), GBINS - 1);
        atomicAdd(&lh[bin], 1);
        atomicAdd(&ls[bin], v);
    }
    __syncthreads();

    const size_t base = ((size_t)b * HB + ci) * GBINS;
#pragma unroll
    for (int j = 0; j < GBINS / 256; j++) {
        int bin = tid + j * 256;
        ghc[base + bin] = lh[bin];
        gsc[base + bin] = ls[bin];
    }
}

// ---------------------------------------------------------------- k_sel
// One block (1024 thr) per batch: merge HB copies (plain loads, fixed
// order), pair suffix-scan -> boundary bin + rank, bin-mean approximation.
// Overwrite-idempotent: pure function of ghc/gsc/np_b -> safe to launch 3x.
__global__ __launch_bounds__(1024) void k_sel(
    const int*   __restrict__ ghc,
    const float* __restrict__ gsc,
    const int*   __restrict__ num_pos_b,
    float* __restrict__ lc2)
{
    __shared__ int   wtot[16];
    __shared__ int   s_B0, s_r;
    __shared__ float red_f[16];

    const int b = blockIdx.x;
    const int tid = threadIdx.x;
    const int lane = tid & 63;
    const int wave = tid >> 6;

    int   c0 = 0, c1 = 0;
    float m0 = 0.0f, m1 = 0.0f;
    const size_t base = (size_t)b * HB * GBINS;
#pragma unroll
    for (int c = 0; c < HB; c++) {
        c0 += ghc[base + (size_t)c * GBINS + 2 * tid];
        c1 += ghc[base + (size_t)c * GBINS + 2 * tid + 1];
        m0 += gsc[base + (size_t)c * GBINS + 2 * tid];
        m1 += gsc[base + (size_t)c * GBINS + 2 * tid + 1];
    }

    const int np = num_pos_b[b];
    const int kk = min(max(3 * np, 1), NPRIOR - 1);

    const int ps = c0 + c1;
    int incl = ps;
#pragma unroll
    for (int off = 1; off < 64; off <<= 1) {
        int t = __shfl_down(incl, off);
        incl += (lane + off < 64) ? t : 0;
    }
    if (lane == 0) wtot[wave] = incl;
    __syncthreads();
    int hi = 0;
#pragma unroll
    for (int w = 0; w < 16; w++) if (w > wave) hi += wtot[w];
    const int suf = (incl - ps) + hi;
    if (suf < kk && kk <= suf + c1)          { s_B0 = 2 * tid + 1; s_r = kk - suf; }
    const int suf1 = suf + c1;
    if (suf1 < kk && kk <= suf1 + c0)        { s_B0 = 2 * tid;     s_r = kk - suf1; }
    __syncthreads();

    const int B0 = s_B0;
    const int r  = s_r;

    float sg = 0.0f;
    if (2 * tid     > B0) sg += m0;
    if (2 * tid + 1 > B0) sg += m1;
    if      (2 * tid     == B0) sg += (float)r * (m0 / (float)c0);
    else if (2 * tid + 1 == B0) sg += (float)r * (m1 / (float)c1);

    for (int off = 32; off; off >>= 1) sg += __shfl_xor(sg, off);
    if (lane == 0) red_f[wave] = sg;
    __syncthreads();
    if (tid == 0) {
        float s = 0.0f;
#pragma unroll
        for (int w = 0; w < 16; w++) s += red_f[w];
        lc2[b] = s;
    }
}

// ---------------------------------------------------------------- k_final
__global__ __launch_bounds__(1024) void k_final(
    const float* __restrict__ lc_part, const float* __restrict__ lc2,
    const float* __restrict__ ll_b, const int* __restrict__ np_b,
    float* __restrict__ out)
{
    __shared__ float rf[16][2];
    __shared__ int   rn[16];
    const int tid = threadIdx.x;
    float lc = 0.0f;
    for (int i = tid; i < CE_GRID; i += 1024) lc += lc_part[i];
    float ll = 0.0f; int np = 0;
    if (tid < BATCH) { lc += lc2[tid]; ll = ll_b[tid]; np = np_b[tid]; }
    for (int off = 32; off; off >>= 1) {
        lc += __shfl_xor(lc, off);
        ll += __shfl_xor(ll, off);
        np += __shfl_xor(np, off);
    }
    const int lane = tid & 63, wave = tid >> 6;
    if (lane == 0) { rf[wave][0] = lc; rf[wave][1] = ll; rn[wave] = np; }
    __syncthreads();
    if (tid == 0) {
        float lcT = 0.0f, llT = 0.0f; int npT = 0;
        for (int w = 0; w < 16; w++) { lcT += rf[w][0]; llT += rf[w][1]; npT += rn[w]; }
        float N = fmaxf((float)npT, 1.0f);
        out[0] = llT / N;
        out[1] = lcT / N;
    }
}

// ---------------------------------------------------------------- launch
// ATTRIBUTION ROUND: k_hist and k_sel each launched 3x (idempotent).
// dur = 128.7 + 2*(H+S)  ->  tail cost measured directly.
extern "C" void kernel_launch(void* const* d_in, const int* in_sizes, int n_in,
                              void* d_out, int out_size, void* d_ws, size_t ws_size,
                              hipStream_t stream)
{
    const float* loc_data  = (const float*)d_in[0];
    const float* conf_data = (const float*)d_in[1];
    const float* gt_boxes  = (const float*)d_in[2];
    const int*   gt_labels = (const int*)d_in[3];
    const float* priors    = (const float*)d_in[4];
    float* out = (float*)d_out;

    char* ws = (char*)d_ws;
    float* ll_b     = (float*)(ws + 0);
    int*   np_b     = (int*)(ws + 256);
    float* lc2      = (float*)(ws + 512);
    float* lc_part  = (float*)(ws + 1024);                       // 24576 B
    int*   conf_t   = (int*)(ws + 32768);                        // 2.24 MB
    float* mine     = (float*)(ws + 32768 + (size_t)BATCH * NPRIOR * 4);
    int*   ghc      = (int*)(ws + 16777216);                     // 8 MB
    float* gsc      = (float*)(ws + 33554432);                   // 8 MB

    hipLaunchKernelGGL(k_match, dim3(BATCH), dim3(1024), 0, stream,
                       loc_data, gt_boxes, gt_labels, priors, conf_t, np_b, ll_b);
    hipLaunchKernelGGL(k_ce, dim3(CE_GRID), dim3(64), 0, stream,
                       conf_data, conf_t, mine, lc_part);
    hipLaunchKernelGGL(k_hist, dim3(HB, BATCH), dim3(256), 0, stream,
                       mine, ghc, gsc);
    hipLaunchKernelGGL(k_hist, dim3(HB, BATCH), dim3(256), 0, stream,
                       mine, ghc, gsc);
    hipLaunchKernelGGL(k_hist, dim3(HB, BATCH), dim3(256), 0, stream,
                       mine, ghc, gsc);
    hipLaunchKernelGGL(k_sel, dim3(BATCH), dim3(1024), 0, stream,
                       ghc, gsc, np_b, lc2);
    hipLaunchKernelGGL(k_sel, dim3(BATCH), dim3(1024), 0, stream,
                       ghc, gsc, np_b, lc2);
    hipLaunchKernelGGL(k_sel, dim3(BATCH), dim3(1024), 0, stream,
                       ghc, gsc, np_b, lc2);
    hipLaunchKernelGGL(k_final, dim3(1), dim3(1024), 0, stream,
                       lc_part, lc2, ll_b, np_b, out);
}

// Round 19
// 129.346 us; speedup vs baseline: 1.2037x; 1.2037x over previous
//
#include <hip/hip_runtime.h>
#include <math.h>

#define BATCH 64
#define NOBJ 16
#define NPRIOR 8732
#define NC 91
#define IMG 300.0f
#define GPB 1092                   // 8-row groups per batch (k_ce)
#define NGROUP (GPB * BATCH)       // 69888
#define CE_GRID 6144               // one-wave blocks
#define GBINS 2048                 // histogram bins: bin = min(2047, v*128)
#define HB 16                      // hist blocks (= private copies) per batch
#define HCHUNK 546                 // priors per hist block (16*546 >= 8732)

// ---------------------------------------------------------------- k_match
// R18 attribution: k_match was ~78us — DS-pipe-bound on 720 LDS box reads
// per thread in phase 1 (16 obj x 5 fields x 9 p-iters). Fix: hoist the 16
// block-uniform boxes into per-thread REGISTER arrays (fully unrolled copy,
// static indexing only) — phase 1 becomes pure VALU (~6us model).
__global__ __launch_bounds__(1024) void k_match(
    const float* __restrict__ loc_data,
    const float* __restrict__ gt_boxes,
    const int*   __restrict__ gt_labels,
    const float* __restrict__ priors,
    int*   __restrict__ conf_t,
    int*   __restrict__ num_pos_b,
    float* __restrict__ ll_b)
{
    __shared__ float s_ov[NPRIOR];
    __shared__ unsigned char s_idx[NPRIOR];
    __shared__ float bx0[NOBJ], by0[NOBJ], bx1[NOBJ], by1[NOBJ], barea[NOBJ];
    __shared__ int   blab[NOBJ];
    __shared__ float rv[NOBJ][16];
    __shared__ int   ri[NOBJ][16];
    __shared__ int   bpi[NOBJ];
    __shared__ float red_f[16];
    __shared__ int   red_i[16];

    const int b    = blockIdx.x;
    const int tid  = threadIdx.x;
    const int lane = tid & 63;
    const int wave = tid >> 6;

    if (tid < NOBJ) {
        float4 g = ((const float4*)gt_boxes)[(size_t)b * NOBJ + tid];
        float x0 = g.x * (1.0f / IMG), y0 = g.y * (1.0f / IMG);
        float x1 = g.z * (1.0f / IMG), y1 = g.w * (1.0f / IMG);
        bx0[tid] = x0; by0[tid] = y0; bx1[tid] = x1; by1[tid] = y1;
        barea[tid] = (x1 - x0) * (y1 - y0);
        blab[tid] = gt_labels[b * NOBJ + tid];
    }
    __syncthreads();

    // hoist boxes LDS -> registers (static indexing; ~80 VGPR, fits 512 cap)
    float rb0[NOBJ], rb1[NOBJ], rb2[NOBJ], rb3[NOBJ], rar[NOBJ];
#pragma unroll
    for (int j = 0; j < NOBJ; j++) {
        rb0[j] = bx0[j]; rb1[j] = by0[j];
        rb2[j] = bx1[j]; rb3[j] = by1[j];
        rar[j] = barea[j];
    }

    float bv[NOBJ];
    int   bi[NOBJ];
#pragma unroll
    for (int j = 0; j < NOBJ; j++) { bv[j] = -1.0f; bi[j] = 0x7fffffff; }

    for (int p = tid; p < NPRIOR; p += 1024) {
        float4 pr = ((const float4*)priors)[p];
        float cx = pr.x, cy = pr.y, w = pr.z, h = pr.w;
        float px0 = cx - 0.5f * w, py0 = cy - 0.5f * h;
        float px1 = cx + 0.5f * w, py1 = cy + 0.5f * h;
        float pa = w * h;
        float maxv = -1.0f; int maxj = 0;
#pragma unroll
        for (int j = 0; j < NOBJ; j++) {
            float ltx = fmaxf(rb0[j], px0), lty = fmaxf(rb1[j], py0);
            float rbx = fminf(rb2[j], px1), rby = fminf(rb3[j], py1);
            float iw = fmaxf(rbx - ltx, 0.0f), ih = fmaxf(rby - lty, 0.0f);
            float inter = iw * ih;
            float iou = inter / (rar[j] + pa - inter);
            if (iou > maxv) { maxv = iou; maxj = j; }
            if (iou > bv[j]) { bv[j] = iou; bi[j] = p; }
        }
        s_ov[p]  = maxv;
        s_idx[p] = (unsigned char)maxj;
    }

#pragma unroll
    for (int j = 0; j < NOBJ; j++) {
        float v = bv[j]; int ix = bi[j];
        for (int off = 32; off; off >>= 1) {
            float v2 = __shfl_xor(v, off);
            int   i2 = __shfl_xor(ix, off);
            if (v2 > v || (v2 == v && i2 < ix)) { v = v2; ix = i2; }
        }
        if (lane == 0) { rv[j][wave] = v; ri[j][wave] = ix; }
    }
    __syncthreads();
    if (tid < NOBJ) {
        int j = tid;
        float v = rv[j][0]; int ix = ri[j][0];
        for (int w2 = 1; w2 < 16; w2++) {
            float v2 = rv[j][w2]; int i2 = ri[j][w2];
            if (v2 > v || (v2 == v && i2 < ix)) { v = v2; ix = i2; }
        }
        bpi[j] = ix;
    }
    __syncthreads();
    if (tid == 0) {
        for (int j = 0; j < NOBJ; j++) s_ov[bpi[j]] = 2.0f;
        for (int j = 0; j < NOBJ; j++) s_idx[bpi[j]] = (unsigned char)j;
    }
    __syncthreads();

    int np_local = 0;
    float ll_local = 0.0f;
    for (int p = tid; p < NPRIOR; p += 1024) {
        float ov = s_ov[p];
        int ti = (int)s_idx[p];
        int conf = (ov < 0.5f) ? 0 : blab[ti];
        conf_t[(size_t)b * NPRIOR + p] = conf;
        if (conf > 0) {
            np_local++;
            float4 pr = ((const float4*)priors)[p];
            float cx = pr.x, cy = pr.y, w = pr.z, h = pr.w;
            float mx0 = bx0[ti], my0 = by0[ti], mx1 = bx1[ti], my1 = by1[ti];
            float g0 = ((mx0 + mx1) * 0.5f - cx) / (0.1f * w);
            float g1 = ((my0 + my1) * 0.5f - cy) / (0.1f * h);
            float g2 = logf((mx1 - mx0) / w) * 5.0f;
            float g3 = logf((my1 - my0) / h) * 5.0f;
            float4 lv = ((const float4*)loc_data)[(size_t)b * NPRIOR + p];
            float d0 = lv.x - g0, d1 = lv.y - g1, d2 = lv.z - g2, d3 = lv.w - g3;
            float a0 = fabsf(d0), a1 = fabsf(d1), a2 = fabsf(d2), a3 = fabsf(d3);
            ll_local += (a0 < 1.f ? 0.5f * d0 * d0 : a0 - 0.5f)
                      + (a1 < 1.f ? 0.5f * d1 * d1 : a1 - 0.5f)
                      + (a2 < 1.f ? 0.5f * d2 * d2 : a2 - 0.5f)
                      + (a3 < 1.f ? 0.5f * d3 * d3 : a3 - 0.5f);
        }
    }
    for (int off = 32; off; off >>= 1) {
        ll_local += __shfl_xor(ll_local, off);
        np_local += __shfl_xor(np_local, off);
    }
    if (lane == 0) { red_f[wave] = ll_local; red_i[wave] = np_local; }
    __syncthreads();
    if (tid == 0) {
        float ll = 0.0f; int np = 0;
        for (int w2 = 0; w2 < 16; w2++) { ll += red_f[w2]; np += red_i[w2]; }
        num_pos_b[b] = np;
        ll_b[b] = ll;
    }
}

// ---------------------------------------------------------------- k_ce
// One-wave persistent blocks, zero barriers, depth-2 register pipeline.

#define CE_ISSUE(gg, R0, R1, R2, NF)                                           \
    {   int b_ = (gg) / GPB, ci_ = (gg) - b_ * GPB;                            \
        int p0_ = ci_ * 8;                                                     \
        int rows_ = min(8, NPRIOR - p0_);                                      \
        NF = (rows_ * NC) >> 2;                                                \
        const float4* s_ = (const float4*)(conf_data + ((size_t)b_ * NPRIOR + p0_) * NC); \
        R0 = s_[tid];                                                          \
        if (tid + 64  < NF) R1 = s_[tid + 64];                                 \
        if (tid + 128 < NF) R2 = s_[tid + 128]; }

#define CT_LOAD(gg)                                                            \
    ( conf_t[(size_t)((gg) / GPB) * NPRIOR + ((gg) - ((gg) / GPB) * GPB) * 8 + (tid >> 3)] )

#define CE_WRITE(BUF, R0, R1, R2, NF)                                          \
    {   float4* d_ = (float4*)sbuf[BUF];                                       \
        d_[tid] = R0;                                                          \
        if (tid + 64  < NF) d_[tid + 64]  = R1;                                \
        if (tid + 128 < NF) d_[tid + 128] = R2; }

#define CE_COMPUTE(gg, BUF, TG)                                                \
    {   int b_ = (gg) / GPB, ci_ = (gg) - b_ * GPB;                            \
        int p0_ = ci_ * 8;                                                     \
        int rows_ = min(8, NPRIOR - p0_);                                      \
        int rr_ = tid >> 3, q_ = tid & 7;                                      \
        if (rr_ < rows_) {                                                     \
            const float* row_ = sbuf[BUF] + rr_ * NC;                          \
            float s_ = 0.0f;                                                   \
            _Pragma("unroll")                                                  \
            for (int i_ = q_; i_ < NC; i_ += 8) s_ += __expf(row_[i_]);        \
            s_ += __shfl_xor(s_, 1);                                           \
            s_ += __shfl_xor(s_, 2);                                           \
            s_ += __shfl_xor(s_, 4);                                           \
            if (q_ == 0) {                                                     \
                size_t o_ = (size_t)b_ * NPRIOR + p0_ + rr_;                   \
                int tgt_ = TG;                                                 \
                float ce_ = __logf(s_) - row_[tgt_];                           \
                if (tgt_ > 0) { pos_acc += ce_; mine[o_] = 0.0f; }             \
                else          { mine[o_] = fmaxf(ce_, 0.0f); }                 \
            } } }

__global__ __launch_bounds__(64) void k_ce(
    const float* __restrict__ conf_data,
    const int*   __restrict__ conf_t,
    float* __restrict__ mine,
    float* __restrict__ lc_part)
{
    __shared__ float sbuf[2][8 * NC];
    const int tid = threadIdx.x;
    const int G = CE_GRID;

    float4 a0, a1, a2, b0, b1, b2;
    int nfA = 0, nfB = 0;
    float pos_acc = 0.0f;

    int g = blockIdx.x;
    CE_ISSUE(g, a0, a1, a2, nfA);
    int tcur = CT_LOAD(g);
    if (g + G < NGROUP) CE_ISSUE(g + G, b0, b1, b2, nfB);
    CE_WRITE(0, a0, a1, a2, nfA);

    for (; g < NGROUP; g += 2 * G) {
        int tnext = (g + G < NGROUP) ? CT_LOAD(g + G) : 0;
        if (g + 2 * G < NGROUP) CE_ISSUE(g + 2 * G, a0, a1, a2, nfA);
        CE_COMPUTE(g, 0, tcur);
        if (g + G < NGROUP) {
            CE_WRITE(1, b0, b1, b2, nfB);
            int tn2 = (g + 2 * G < NGROUP) ? CT_LOAD(g + 2 * G) : 0;
            if (g + 3 * G < NGROUP) CE_ISSUE(g + 3 * G, b0, b1, b2, nfB);
            CE_COMPUTE(g + G, 1, tnext);
            if (g + 2 * G < NGROUP) CE_WRITE(0, a0, a1, a2, nfA);
            tcur = tn2;
        }
    }

    for (int off = 32; off; off >>= 1) pos_acc += __shfl_xor(pos_acc, off);
    if (tid == 0) lc_part[blockIdx.x] = pos_acc;
}

// ---------------------------------------------------------------- k_hist
// 16 blocks x 256 thr per batch: private LDS histogram (count+sum), plain
// coalesced stores of the private copy to ghc/gsc. No global atomics.
__global__ __launch_bounds__(256) void k_hist(
    const float* __restrict__ mine,
    int*   __restrict__ ghc,          // [B][HB][GBINS]
    float* __restrict__ gsc)          // [B][HB][GBINS]
{
    __shared__ int   lh[GBINS];
    __shared__ float ls[GBINS];

    const int b  = blockIdx.y;
    const int ci = blockIdx.x;
    const int tid = threadIdx.x;
    const int i0 = ci * HCHUNK;
    const int iend = min(i0 + HCHUNK, NPRIOR);

#pragma unroll
    for (int j = 0; j < GBINS / 256; j++) {
        lh[tid + j * 256] = 0;
        ls[tid + j * 256] = 0.0f;
    }
    __syncthreads();

    for (int i = i0 + tid; i < iend; i += 256) {
        float v = mine[(size_t)b * NPRIOR + i];
        int bin = min((int)(v * 128.0f), GBINS - 1);
        atomicAdd(&lh[bin], 1);
        atomicAdd(&ls[bin], v);
    }
    __syncthreads();

    const size_t base = ((size_t)b * HB + ci) * GBINS;
#pragma unroll
    for (int j = 0; j < GBINS / 256; j++) {
        int bin = tid + j * 256;
        ghc[base + bin] = lh[bin];
        gsc[base + bin] = ls[bin];
    }
}

// ---------------------------------------------------------------- k_sel
// One block (1024 thr) per batch: merge HB copies (plain loads, fixed
// order), pair suffix-scan -> boundary bin + rank, bin-mean approximation.
__global__ __launch_bounds__(1024) void k_sel(
    const int*   __restrict__ ghc,
    const float* __restrict__ gsc,
    const int*   __restrict__ num_pos_b,
    float* __restrict__ lc2)
{
    __shared__ int   wtot[16];
    __shared__ int   s_B0, s_r;
    __shared__ float red_f[16];

    const int b = blockIdx.x;
    const int tid = threadIdx.x;
    const int lane = tid & 63;
    const int wave = tid >> 6;

    int   c0 = 0, c1 = 0;
    float m0 = 0.0f, m1 = 0.0f;
    const size_t base = (size_t)b * HB * GBINS;
#pragma unroll
    for (int c = 0; c < HB; c++) {
        c0 += ghc[base + (size_t)c * GBINS + 2 * tid];
        c1 += ghc[base + (size_t)c * GBINS + 2 * tid + 1];
        m0 += gsc[base + (size_t)c * GBINS + 2 * tid];
        m1 += gsc[base + (size_t)c * GBINS + 2 * tid + 1];
    }

    const int np = num_pos_b[b];
    const int kk = min(max(3 * np, 1), NPRIOR - 1);

    const int ps = c0 + c1;
    int incl = ps;
#pragma unroll
    for (int off = 1; off < 64; off <<= 1) {
        int t = __shfl_down(incl, off);
        incl += (lane + off < 64) ? t : 0;
    }
    if (lane == 0) wtot[wave] = incl;
    __syncthreads();
    int hi = 0;
#pragma unroll
    for (int w = 0; w < 16; w++) if (w > wave) hi += wtot[w];
    const int suf = (incl - ps) + hi;
    if (suf < kk && kk <= suf + c1)          { s_B0 = 2 * tid + 1; s_r = kk - suf; }
    const int suf1 = suf + c1;
    if (suf1 < kk && kk <= suf1 + c0)        { s_B0 = 2 * tid;     s_r = kk - suf1; }
    __syncthreads();

    const int B0 = s_B0;
    const int r  = s_r;

    float sg = 0.0f;
    if (2 * tid     > B0) sg += m0;
    if (2 * tid + 1 > B0) sg += m1;
    if      (2 * tid     == B0) sg += (float)r * (m0 / (float)c0);
    else if (2 * tid + 1 == B0) sg += (float)r * (m1 / (float)c1);

    for (int off = 32; off; off >>= 1) sg += __shfl_xor(sg, off);
    if (lane == 0) red_f[wave] = sg;
    __syncthreads();
    if (tid == 0) {
        float s = 0.0f;
#pragma unroll
        for (int w = 0; w < 16; w++) s += red_f[w];
        lc2[b] = s;
    }
}

// ---------------------------------------------------------------- k_final
__global__ __launch_bounds__(1024) void k_final(
    const float* __restrict__ lc_part, const float* __restrict__ lc2,
    const float* __restrict__ ll_b, const int* __restrict__ np_b,
    float* __restrict__ out)
{
    __shared__ float rf[16][2];
    __shared__ int   rn[16];
    const int tid = threadIdx.x;
    float lc = 0.0f;
    for (int i = tid; i < CE_GRID; i += 1024) lc += lc_part[i];
    float ll = 0.0f; int np = 0;
    if (tid < BATCH) { lc += lc2[tid]; ll = ll_b[tid]; np = np_b[tid]; }
    for (int off = 32; off; off >>= 1) {
        lc += __shfl_xor(lc, off);
        ll += __shfl_xor(ll, off);
        np += __shfl_xor(np, off);
    }
    const int lane = tid & 63, wave = tid >> 6;
    if (lane == 0) { rf[wave][0] = lc; rf[wave][1] = ll; rn[wave] = np; }
    __syncthreads();
    if (tid == 0) {
        float lcT = 0.0f, llT = 0.0f; int npT = 0;
        for (int w = 0; w < 16; w++) { lcT += rf[w][0]; llT += rf[w][1]; npT += rn[w]; }
        float N = fmaxf((float)npT, 1.0f);
        out[0] = llT / N;
        out[1] = lcT / N;
    }
}

// ---------------------------------------------------------------- launch
extern "C" void kernel_launch(void* const* d_in, const int* in_sizes, int n_in,
                              void* d_out, int out_size, void* d_ws, size_t ws_size,
                              hipStream_t stream)
{
    const float* loc_data  = (const float*)d_in[0];
    const float* conf_data = (const float*)d_in[1];
    const float* gt_boxes  = (const float*)d_in[2];
    const int*   gt_labels = (const int*)d_in[3];
    const float* priors    = (const float*)d_in[4];
    float* out = (float*)d_out;

    char* ws = (char*)d_ws;
    float* ll_b     = (float*)(ws + 0);
    int*   np_b     = (int*)(ws + 256);
    float* lc2      = (float*)(ws + 512);
    float* lc_part  = (float*)(ws + 1024);                       // 24576 B
    int*   conf_t   = (int*)(ws + 32768);                        // 2.24 MB
    float* mine     = (float*)(ws + 32768 + (size_t)BATCH * NPRIOR * 4);
    int*   ghc      = (int*)(ws + 16777216);                     // 8 MB
    float* gsc      = (float*)(ws + 33554432);                   // 8 MB

    hipLaunchKernelGGL(k_match, dim3(BATCH), dim3(1024), 0, stream,
                       loc_data, gt_boxes, gt_labels, priors, conf_t, np_b, ll_b);
    hipLaunchKernelGGL(k_ce, dim3(CE_GRID), dim3(64), 0, stream,
                       conf_data, conf_t, mine, lc_part);
    hipLaunchKernelGGL(k_hist, dim3(HB, BATCH), dim3(256), 0, stream,
                       mine, ghc, gsc);
    hipLaunchKernelGGL(k_sel, dim3(BATCH), dim3(1024), 0, stream,
                       ghc, gsc, np_b, lc2);
    hipLaunchKernelGGL(k_final, dim3(1), dim3(1024), 0, stream,
                       lc_part, lc2, ll_b, np_b, out);
}

// Round 20
// 109.595 us; speedup vs baseline: 1.4207x; 1.1802x over previous
//
#include <hip/hip_runtime.h>
#include <math.h>

#define BATCH 64
#define NOBJ 16
#define NPRIOR 8732
#define NC 91
#define IMG 300.0f
#define GPB 1092                   // 8-row groups per batch (k_ce)
#define NGROUP (GPB * BATCH)       // 69888
#define CE_GRID 6144               // one-wave blocks
#define GBINS 2048                 // histogram bins: bin = min(2047, v*128)
#define HB 16                      // hist blocks (= private copies) per batch
#define HCHUNK 546                 // priors per hist block (16*546 >= 8732)
#define MSPLIT 4                   // match blocks per batch
#define SL 2183                    // priors per match slice (4*2183 = 8732)

// ---------------------------------------------------------------- k_match_a
// Heavy phase (IoU) at 4x parallelism: grid (MSPLIT, BATCH). Each block
// computes per-prior best-truth (ov, idx) for its slice -> global, plus
// per-(block, j) best-prior candidates for the cross-slice argmax.
__global__ __launch_bounds__(1024) void k_match_a(
    const float* __restrict__ gt_boxes,
    const float* __restrict__ priors,
    float* __restrict__ ov_g,              // [B][P]
    unsigned char* __restrict__ idx_g,     // [B][P]
    float* __restrict__ candv,             // [B][MSPLIT][NOBJ]
    int*   __restrict__ candi)             // [B][MSPLIT][NOBJ]
{
    __shared__ float bx0[NOBJ], by0[NOBJ], bx1[NOBJ], by1[NOBJ], barea[NOBJ];
    __shared__ float rv[NOBJ][16];
    __shared__ int   ri[NOBJ][16];

    const int b    = blockIdx.y;
    const int blk  = blockIdx.x;
    const int tid  = threadIdx.x;
    const int lane = tid & 63;
    const int wave = tid >> 6;
    const int p0   = blk * SL;
    const int pend = p0 + SL;              // exact (4*2183 = 8732)

    if (tid < NOBJ) {
        float4 g = ((const float4*)gt_boxes)[(size_t)b * NOBJ + tid];
        float x0 = g.x * (1.0f / IMG), y0 = g.y * (1.0f / IMG);
        float x1 = g.z * (1.0f / IMG), y1 = g.w * (1.0f / IMG);
        bx0[tid] = x0; by0[tid] = y0; bx1[tid] = x1; by1[tid] = y1;
        barea[tid] = (x1 - x0) * (y1 - y0);
    }
    __syncthreads();

    float bv[NOBJ];
    int   bi[NOBJ];
#pragma unroll
    for (int j = 0; j < NOBJ; j++) { bv[j] = -1.0f; bi[j] = 0x7fffffff; }

    for (int p = p0 + tid; p < pend; p += 1024) {
        float4 pr = ((const float4*)priors)[p];
        float cx = pr.x, cy = pr.y, w = pr.z, h = pr.w;
        float px0 = cx - 0.5f * w, py0 = cy - 0.5f * h;
        float px1 = cx + 0.5f * w, py1 = cy + 0.5f * h;
        float pa = w * h;
        float maxv = -1.0f; int maxj = 0;
#pragma unroll
        for (int j = 0; j < NOBJ; j++) {
            float ltx = fmaxf(bx0[j], px0), lty = fmaxf(by0[j], py0);
            float rbx = fminf(bx1[j], px1), rby = fminf(by1[j], py1);
            float iw = fmaxf(rbx - ltx, 0.0f), ih = fmaxf(rby - lty, 0.0f);
            float inter = iw * ih;
            float iou = inter / (barea[j] + pa - inter);
            if (iou > maxv) { maxv = iou; maxj = j; }        // first argmax over j
            if (iou > bv[j]) { bv[j] = iou; bi[j] = p; }     // first argmax over p
        }
        ov_g[(size_t)b * NPRIOR + p]  = maxv;
        idx_g[(size_t)b * NPRIOR + p] = (unsigned char)maxj;
    }

    // per-j block-best (tie: smaller p wins; lanes hold ascending p)
#pragma unroll
    for (int j = 0; j < NOBJ; j++) {
        float v = bv[j]; int ix = bi[j];
        for (int off = 32; off; off >>= 1) {
            float v2 = __shfl_xor(v, off);
            int   i2 = __shfl_xor(ix, off);
            if (v2 > v || (v2 == v && i2 < ix)) { v = v2; ix = i2; }
        }
        if (lane == 0) { rv[j][wave] = v; ri[j][wave] = ix; }
    }
    __syncthreads();
    if (tid < NOBJ) {
        int j = tid;
        float v = rv[j][0]; int ix = ri[j][0];
        for (int w2 = 1; w2 < 16; w2++) {
            float v2 = rv[j][w2]; int i2 = ri[j][w2];
            if (v2 > v || (v2 == v && i2 < ix)) { v = v2; ix = i2; }
        }
        size_t o = ((size_t)b * MSPLIT + blk) * NOBJ + j;
        candv[o] = v;
        candi[o] = ix;
    }
}

// ---------------------------------------------------------------- k_bpi
// Reduce the MSPLIT candidate sets per batch -> best prior per truth j.
// Scanning blocks in ascending order preserves the smaller-index tie-break.
__global__ __launch_bounds__(64) void k_bpi(
    const float* __restrict__ candv,
    const int*   __restrict__ candi,
    int* __restrict__ bpi_g)               // [B][NOBJ]
{
    const int b = blockIdx.x;
    const int j = threadIdx.x;
    if (j < NOBJ) {
        size_t base = (size_t)b * MSPLIT * NOBJ + j;
        float v = candv[base]; int ix = candi[base];
#pragma unroll
        for (int c = 1; c < MSPLIT; c++) {
            float v2 = candv[base + c * NOBJ];
            int   i2 = candi[base + c * NOBJ];
            if (v2 > v || (v2 == v && i2 < ix)) { v = v2; ix = i2; }
        }
        bpi_g[b * NOBJ + j] = ix;
    }
}

// ---------------------------------------------------------------- k_match_c
// Conf/loc phase at 4x parallelism. Override semantics: reference scatters
// idx=j for j in ascending order (later j wins on collision) and ov=2.0
// (>= 0.5 -> conf=labels[j] always). Implemented via last-match scan.
__global__ __launch_bounds__(1024) void k_match_c(
    const float* __restrict__ loc_data,
    const float* __restrict__ gt_boxes,
    const int*   __restrict__ gt_labels,
    const float* __restrict__ priors,
    const float* __restrict__ ov_g,
    const unsigned char* __restrict__ idx_g,
    const int*   __restrict__ bpi_g,
    int*   __restrict__ conf_t,
    float* __restrict__ ll_part,           // [B*MSPLIT]
    int*   __restrict__ np_part)           // [B*MSPLIT]
{
    __shared__ float bx0[NOBJ], by0[NOBJ], bx1[NOBJ], by1[NOBJ];
    __shared__ int   blab[NOBJ], bpi_s[NOBJ];
    __shared__ float red_f[16];
    __shared__ int   red_i[16];

    const int b    = blockIdx.y;
    const int blk  = blockIdx.x;
    const int tid  = threadIdx.x;
    const int lane = tid & 63;
    const int wave = tid >> 6;
    const int p0   = blk * SL;
    const int pend = p0 + SL;

    if (tid < NOBJ) {
        float4 g = ((const float4*)gt_boxes)[(size_t)b * NOBJ + tid];
        bx0[tid] = g.x * (1.0f / IMG); by0[tid] = g.y * (1.0f / IMG);
        bx1[tid] = g.z * (1.0f / IMG); by1[tid] = g.w * (1.0f / IMG);
        blab[tid]  = gt_labels[b * NOBJ + tid];
        bpi_s[tid] = bpi_g[b * NOBJ + tid];
    }
    __syncthreads();

    int np_local = 0;
    float ll_local = 0.0f;
    for (int p = p0 + tid; p < pend; p += 1024) {
        float ov = ov_g[(size_t)b * NPRIOR + p];
        int ti = (int)idx_g[(size_t)b * NPRIOR + p];
        int oj = -1;
#pragma unroll
        for (int j = 0; j < NOBJ; j++)
            if (bpi_s[j] == p) oj = j;       // last j wins (in-order scatter)
        int conf;
        if (oj >= 0) { ti = oj; conf = blab[oj]; }   // ov=2.0 >= 0.5
        else         { conf = (ov < 0.5f) ? 0 : blab[ti]; }
        conf_t[(size_t)b * NPRIOR + p] = conf;
        if (conf > 0) {
            np_local++;
            float4 pr = ((const float4*)priors)[p];
            float cx = pr.x, cy = pr.y, w = pr.z, h = pr.w;
            float mx0 = bx0[ti], my0 = by0[ti], mx1 = bx1[ti], my1 = by1[ti];
            float g0 = ((mx0 + mx1) * 0.5f - cx) / (0.1f * w);
            float g1 = ((my0 + my1) * 0.5f - cy) / (0.1f * h);
            float g2 = logf((mx1 - mx0) / w) * 5.0f;
            float g3 = logf((my1 - my0) / h) * 5.0f;
            float4 lv = ((const float4*)loc_data)[(size_t)b * NPRIOR + p];
            float d0 = lv.x - g0, d1 = lv.y - g1, d2 = lv.z - g2, d3 = lv.w - g3;
            float a0 = fabsf(d0), a1 = fabsf(d1), a2 = fabsf(d2), a3 = fabsf(d3);
            ll_local += (a0 < 1.f ? 0.5f * d0 * d0 : a0 - 0.5f)
                      + (a1 < 1.f ? 0.5f * d1 * d1 : a1 - 0.5f)
                      + (a2 < 1.f ? 0.5f * d2 * d2 : a2 - 0.5f)
                      + (a3 < 1.f ? 0.5f * d3 * d3 : a3 - 0.5f);
        }
    }
    for (int off = 32; off; off >>= 1) {
        ll_local += __shfl_xor(ll_local, off);
        np_local += __shfl_xor(np_local, off);
    }
    if (lane == 0) { red_f[wave] = ll_local; red_i[wave] = np_local; }
    __syncthreads();
    if (tid == 0) {
        float ll = 0.0f; int np = 0;
        for (int w2 = 0; w2 < 16; w2++) { ll += red_f[w2]; np += red_i[w2]; }
        ll_part[b * MSPLIT + blk] = ll;
        np_part[b * MSPLIT + blk] = np;
    }
}

// ---------------------------------------------------------------- k_ce
// One-wave persistent blocks, zero barriers, depth-2 register pipeline.

#define CE_ISSUE(gg, R0, R1, R2, NF)                                           \
    {   int b_ = (gg) / GPB, ci_ = (gg) - b_ * GPB;                            \
        int p0_ = ci_ * 8;                                                     \
        int rows_ = min(8, NPRIOR - p0_);                                      \
        NF = (rows_ * NC) >> 2;                                                \
        const float4* s_ = (const float4*)(conf_data + ((size_t)b_ * NPRIOR + p0_) * NC); \
        R0 = s_[tid];                                                          \
        if (tid + 64  < NF) R1 = s_[tid + 64];                                 \
        if (tid + 128 < NF) R2 = s_[tid + 128]; }

#define CT_LOAD(gg)                                                            \
    ( conf_t[(size_t)((gg) / GPB) * NPRIOR + ((gg) - ((gg) / GPB) * GPB) * 8 + (tid >> 3)] )

#define CE_WRITE(BUF, R0, R1, R2, NF)                                          \
    {   float4* d_ = (float4*)sbuf[BUF];                                       \
        d_[tid] = R0;                                                          \
        if (tid + 64  < NF) d_[tid + 64]  = R1;                                \
        if (tid + 128 < NF) d_[tid + 128] = R2; }

#define CE_COMPUTE(gg, BUF, TG)                                                \
    {   int b_ = (gg) / GPB, ci_ = (gg) - b_ * GPB;                            \
        int p0_ = ci_ * 8;                                                     \
        int rows_ = min(8, NPRIOR - p0_);                                      \
        int rr_ = tid >> 3, q_ = tid & 7;                                      \
        if (rr_ < rows_) {                                                     \
            const float* row_ = sbuf[BUF] + rr_ * NC;                          \
            float s_ = 0.0f;                                                   \
            _Pragma("unroll")                                                  \
            for (int i_ = q_; i_ < NC; i_ += 8) s_ += __expf(row_[i_]);        \
            s_ += __shfl_xor(s_, 1);                                           \
            s_ += __shfl_xor(s_, 2);                                           \
            s_ += __shfl_xor(s_, 4);                                           \
            if (q_ == 0) {                                                     \
                size_t o_ = (size_t)b_ * NPRIOR + p0_ + rr_;                   \
                int tgt_ = TG;                                                 \
                float ce_ = __logf(s_) - row_[tgt_];                           \
                if (tgt_ > 0) { pos_acc += ce_; mine[o_] = 0.0f; }             \
                else          { mine[o_] = fmaxf(ce_, 0.0f); }                 \
            } } }

__global__ __launch_bounds__(64) void k_ce(
    const float* __restrict__ conf_data,
    const int*   __restrict__ conf_t,
    float* __restrict__ mine,
    float* __restrict__ lc_part)
{
    __shared__ float sbuf[2][8 * NC];
    const int tid = threadIdx.x;
    const int G = CE_GRID;

    float4 a0, a1, a2, b0, b1, b2;
    int nfA = 0, nfB = 0;
    float pos_acc = 0.0f;

    int g = blockIdx.x;
    CE_ISSUE(g, a0, a1, a2, nfA);
    int tcur = CT_LOAD(g);
    if (g + G < NGROUP) CE_ISSUE(g + G, b0, b1, b2, nfB);
    CE_WRITE(0, a0, a1, a2, nfA);

    for (; g < NGROUP; g += 2 * G) {
        int tnext = (g + G < NGROUP) ? CT_LOAD(g + G) : 0;
        if (g + 2 * G < NGROUP) CE_ISSUE(g + 2 * G, a0, a1, a2, nfA);
        CE_COMPUTE(g, 0, tcur);
        if (g + G < NGROUP) {
            CE_WRITE(1, b0, b1, b2, nfB);
            int tn2 = (g + 2 * G < NGROUP) ? CT_LOAD(g + 2 * G) : 0;
            if (g + 3 * G < NGROUP) CE_ISSUE(g + 3 * G, b0, b1, b2, nfB);
            CE_COMPUTE(g + G, 1, tnext);
            if (g + 2 * G < NGROUP) CE_WRITE(0, a0, a1, a2, nfA);
            tcur = tn2;
        }
    }

    for (int off = 32; off; off >>= 1) pos_acc += __shfl_xor(pos_acc, off);
    if (tid == 0) lc_part[blockIdx.x] = pos_acc;
}

// ---------------------------------------------------------------- k_hist
__global__ __launch_bounds__(256) void k_hist(
    const float* __restrict__ mine,
    int*   __restrict__ ghc,          // [B][HB][GBINS]
    float* __restrict__ gsc)          // [B][HB][GBINS]
{
    __shared__ int   lh[GBINS];
    __shared__ float ls[GBINS];

    const int b  = blockIdx.y;
    const int ci = blockIdx.x;
    const int tid = threadIdx.x;
    const int i0 = ci * HCHUNK;
    const int iend = min(i0 + HCHUNK, NPRIOR);

#pragma unroll
    for (int j = 0; j < GBINS / 256; j++) {
        lh[tid + j * 256] = 0;
        ls[tid + j * 256] = 0.0f;
    }
    __syncthreads();

    for (int i = i0 + tid; i < iend; i += 256) {
        float v = mine[(size_t)b * NPRIOR + i];
        int bin = min((int)(v * 128.0f), GBINS - 1);
        atomicAdd(&lh[bin], 1);
        atomicAdd(&ls[bin], v);
    }
    __syncthreads();

    const size_t base = ((size_t)b * HB + ci) * GBINS;
#pragma unroll
    for (int j = 0; j < GBINS / 256; j++) {
        int bin = tid + j * 256;
        ghc[base + bin] = lh[bin];
        gsc[base + bin] = ls[bin];
    }
}

// ---------------------------------------------------------------- k_sel
__global__ __launch_bounds__(1024) void k_sel(
    const int*   __restrict__ ghc,
    const float* __restrict__ gsc,
    const int*   __restrict__ np_part,
    float* __restrict__ lc2)
{
    __shared__ int   wtot[16];
    __shared__ int   s_B0, s_r;
    __shared__ float red_f[16];

    const int b = blockIdx.x;
    const int tid = threadIdx.x;
    const int lane = tid & 63;
    const int wave = tid >> 6;

    int   c0 = 0, c1 = 0;
    float m0 = 0.0f, m1 = 0.0f;
    const size_t base = (size_t)b * HB * GBINS;
#pragma unroll
    for (int c = 0; c < HB; c++) {
        c0 += ghc[base + (size_t)c * GBINS + 2 * tid];
        c1 += ghc[base + (size_t)c * GBINS + 2 * tid + 1];
        m0 += gsc[base + (size_t)c * GBINS + 2 * tid];
        m1 += gsc[base + (size_t)c * GBINS + 2 * tid + 1];
    }

    int np = np_part[b * MSPLIT] + np_part[b * MSPLIT + 1]
           + np_part[b * MSPLIT + 2] + np_part[b * MSPLIT + 3];
    const int kk = min(max(3 * np, 1), NPRIOR - 1);

    const int ps = c0 + c1;
    int incl = ps;
#pragma unroll
    for (int off = 1; off < 64; off <<= 1) {
        int t = __shfl_down(incl, off);
        incl += (lane + off < 64) ? t : 0;
    }
    if (lane == 0) wtot[wave] = incl;
    __syncthreads();
    int hi = 0;
#pragma unroll
    for (int w = 0; w < 16; w++) if (w > wave) hi += wtot[w];
    const int suf = (incl - ps) + hi;
    if (suf < kk && kk <= suf + c1)          { s_B0 = 2 * tid + 1; s_r = kk - suf; }
    const int suf1 = suf + c1;
    if (suf1 < kk && kk <= suf1 + c0)        { s_B0 = 2 * tid;     s_r = kk - suf1; }
    __syncthreads();

    const int B0 = s_B0;
    const int r  = s_r;

    float sg = 0.0f;
    if (2 * tid     > B0) sg += m0;
    if (2 * tid + 1 > B0) sg += m1;
    if      (2 * tid     == B0) sg += (float)r * (m0 / (float)c0);
    else if (2 * tid + 1 == B0) sg += (float)r * (m1 / (float)c1);

    for (int off = 32; off; off >>= 1) sg += __shfl_xor(sg, off);
    if (lane == 0) red_f[wave] = sg;
    __syncthreads();
    if (tid == 0) {
        float s = 0.0f;
#pragma unroll
        for (int w = 0; w < 16; w++) s += red_f[w];
        lc2[b] = s;
    }
}

// ---------------------------------------------------------------- k_final
__global__ __launch_bounds__(1024) void k_final(
    const float* __restrict__ lc_part, const float* __restrict__ lc2,
    const float* __restrict__ ll_part, const int* __restrict__ np_part,
    float* __restrict__ out)
{
    __shared__ float rf[16][2];
    __shared__ int   rn[16];
    const int tid = threadIdx.x;
    float lc = 0.0f;
    for (int i = tid; i < CE_GRID; i += 1024) lc += lc_part[i];
    float ll = 0.0f; int np = 0;
    if (tid < BATCH) lc += lc2[tid];
    if (tid < BATCH * MSPLIT) { ll = ll_part[tid]; np = np_part[tid]; }
    for (int off = 32; off; off >>= 1) {
        lc += __shfl_xor(lc, off);
        ll += __shfl_xor(ll, off);
        np += __shfl_xor(np, off);
    }
    const int lane = tid & 63, wave = tid >> 6;
    if (lane == 0) { rf[wave][0] = lc; rf[wave][1] = ll; rn[wave] = np; }
    __syncthreads();
    if (tid == 0) {
        float lcT = 0.0f, llT = 0.0f; int npT = 0;
        for (int w = 0; w < 16; w++) { lcT += rf[w][0]; llT += rf[w][1]; npT += rn[w]; }
        float N = fmaxf((float)npT, 1.0f);
        out[0] = llT / N;
        out[1] = lcT / N;
    }
}

// ---------------------------------------------------------------- launch
extern "C" void kernel_launch(void* const* d_in, const int* in_sizes, int n_in,
                              void* d_out, int out_size, void* d_ws, size_t ws_size,
                              hipStream_t stream)
{
    const float* loc_data  = (const float*)d_in[0];
    const float* conf_data = (const float*)d_in[1];
    const float* gt_boxes  = (const float*)d_in[2];
    const int*   gt_labels = (const int*)d_in[3];
    const float* priors    = (const float*)d_in[4];
    float* out = (float*)d_out;

    char* ws = (char*)d_ws;
    float* ll_part  = (float*)(ws + 0);                          // 256 floats
    int*   np_part  = (int*)(ws + 1024);                         // 256 ints
    float* lc2      = (float*)(ws + 2048);                       // 64 floats
    float* lc_part  = (float*)(ws + 4096);                       // 6144 floats
    int*   conf_t   = (int*)(ws + 32768);                        // 2.24 MB
    float* mine     = (float*)(ws + 32768 + 2235392);            // 2.24 MB
    float* ov_g     = (float*)(ws + 4503552);                    // 2.24 MB
    unsigned char* idx_g = (unsigned char*)(ws + 6738944);       // 0.56 MB
    float* candv    = (float*)(ws + 7297792);                    // 16 KB
    int*   candi    = (int*)(ws + 7314176);                      // 16 KB
    int*   bpi_g    = (int*)(ws + 7330560);                      // 4 KB
    int*   ghc      = (int*)(ws + 16777216);                     // 8 MB
    float* gsc      = (float*)(ws + 25165824);                   // 8 MB

    hipLaunchKernelGGL(k_match_a, dim3(MSPLIT, BATCH), dim3(1024), 0, stream,
                       gt_boxes, priors, ov_g, idx_g, candv, candi);
    hipLaunchKernelGGL(k_bpi, dim3(BATCH), dim3(64), 0, stream,
                       candv, candi, bpi_g);
    hipLaunchKernelGGL(k_match_c, dim3(MSPLIT, BATCH), dim3(1024), 0, stream,
                       loc_data, gt_boxes, gt_labels, priors, ov_g, idx_g,
                       bpi_g, conf_t, ll_part, np_part);
    hipLaunchKernelGGL(k_ce, dim3(CE_GRID), dim3(64), 0, stream,
                       conf_data, conf_t, mine, lc_part);
    hipLaunchKernelGGL(k_hist, dim3(HB, BATCH), dim3(256), 0, stream,
                       mine, ghc, gsc);
    hipLaunchKernelGGL(k_sel, dim3(BATCH), dim3(1024), 0, stream,
                       ghc, gsc, np_part, lc2);
    hipLaunchKernelGGL(k_final, dim3(1), dim3(1024), 0, stream,
                       lc_part, lc2, ll_part, np_part, out);
}

// Round 21
// 100.636 us; speedup vs baseline: 1.5472x; 1.0890x over previous
//
#include <hip/hip_runtime.h>
#include <math.h>

#define BATCH 64
#define NOBJ 16
#define NPRIOR 8732
#define NC 91
#define IMG 300.0f
#define GPB 1092                   // 8-row groups per batch (k_ce)
#define NGROUP (GPB * BATCH)       // 69888
#define CE_GRID 6144               // one-wave blocks
#define GBINS 2048                 // histogram bins: bin = min(2047, v*128)
#define HB 16                      // hist blocks (= private copies) per batch
#define HCHUNK 546                 // priors per hist block
#define MSPLIT 16                  // match blocks per batch
#define SL 546                     // priors per match slice (16*546 >= 8732)

// ---------------------------------------------------------------- k_match_a
// IoU phase at 16x parallelism, 256-thread (4-wave) blocks: 1024 blocks =
// 4/CU, ~2.1 priors/thread. Small blocks + shallow reduction tree (the
// 16-wave barrier-coupled shape was consistently slow this session).
__global__ __launch_bounds__(256) void k_match_a(
    const float* __restrict__ gt_boxes,
    const float* __restrict__ priors,
    float* __restrict__ ov_g,              // [B][P]
    unsigned char* __restrict__ idx_g,     // [B][P]
    float* __restrict__ candv,             // [B][MSPLIT][NOBJ]
    int*   __restrict__ candi)             // [B][MSPLIT][NOBJ]
{
    __shared__ float bx0[NOBJ], by0[NOBJ], bx1[NOBJ], by1[NOBJ], barea[NOBJ];
    __shared__ float rv[NOBJ][4];
    __shared__ int   ri[NOBJ][4];

    const int b    = blockIdx.y;
    const int blk  = blockIdx.x;
    const int tid  = threadIdx.x;
    const int lane = tid & 63;
    const int wave = tid >> 6;             // 0..3
    const int p0   = blk * SL;
    const int pend = min(p0 + SL, NPRIOR);

    if (tid < NOBJ) {
        float4 g = ((const float4*)gt_boxes)[(size_t)b * NOBJ + tid];
        float x0 = g.x * (1.0f / IMG), y0 = g.y * (1.0f / IMG);
        float x1 = g.z * (1.0f / IMG), y1 = g.w * (1.0f / IMG);
        bx0[tid] = x0; by0[tid] = y0; bx1[tid] = x1; by1[tid] = y1;
        barea[tid] = (x1 - x0) * (y1 - y0);
    }
    __syncthreads();

    float bv[NOBJ];
    int   bi[NOBJ];
#pragma unroll
    for (int j = 0; j < NOBJ; j++) { bv[j] = -1.0f; bi[j] = 0x7fffffff; }

    for (int p = p0 + tid; p < pend; p += 256) {
        float4 pr = ((const float4*)priors)[p];
        float cx = pr.x, cy = pr.y, w = pr.z, h = pr.w;
        float px0 = cx - 0.5f * w, py0 = cy - 0.5f * h;
        float px1 = cx + 0.5f * w, py1 = cy + 0.5f * h;
        float pa = w * h;
        float maxv = -1.0f; int maxj = 0;
#pragma unroll
        for (int j = 0; j < NOBJ; j++) {
            float ltx = fmaxf(bx0[j], px0), lty = fmaxf(by0[j], py0);
            float rbx = fminf(bx1[j], px1), rby = fminf(by1[j], py1);
            float iw = fmaxf(rbx - ltx, 0.0f), ih = fmaxf(rby - lty, 0.0f);
            float inter = iw * ih;
            float iou = inter / (barea[j] + pa - inter);
            if (iou > maxv) { maxv = iou; maxj = j; }        // first argmax over j
            if (iou > bv[j]) { bv[j] = iou; bi[j] = p; }     // first argmax over p
        }
        ov_g[(size_t)b * NPRIOR + p]  = maxv;
        idx_g[(size_t)b * NPRIOR + p] = (unsigned char)maxj;
    }

    // per-j block-best (tie: smaller p wins; lanes hold ascending p)
#pragma unroll
    for (int j = 0; j < NOBJ; j++) {
        float v = bv[j]; int ix = bi[j];
        for (int off = 32; off; off >>= 1) {
            float v2 = __shfl_xor(v, off);
            int   i2 = __shfl_xor(ix, off);
            if (v2 > v || (v2 == v && i2 < ix)) { v = v2; ix = i2; }
        }
        if (lane == 0) { rv[j][wave] = v; ri[j][wave] = ix; }
    }
    __syncthreads();
    if (tid < NOBJ) {
        int j = tid;
        float v = rv[j][0]; int ix = ri[j][0];
#pragma unroll
        for (int w2 = 1; w2 < 4; w2++) {
            float v2 = rv[j][w2]; int i2 = ri[j][w2];
            if (v2 > v || (v2 == v && i2 < ix)) { v = v2; ix = i2; }
        }
        size_t o = ((size_t)b * MSPLIT + blk) * NOBJ + j;
        candv[o] = v;
        candi[o] = ix;
    }
}

// ---------------------------------------------------------------- k_bpi
// Reduce MSPLIT candidate sets per batch (ascending block order preserves
// the smaller-index tie-break since slices are ordered by p).
__global__ __launch_bounds__(64) void k_bpi(
    const float* __restrict__ candv,
    const int*   __restrict__ candi,
    int* __restrict__ bpi_g)               // [B][NOBJ]
{
    const int b = blockIdx.x;
    const int j = threadIdx.x;
    if (j < NOBJ) {
        size_t base = (size_t)b * MSPLIT * NOBJ + j;
        float v = candv[base]; int ix = candi[base];
#pragma unroll
        for (int c = 1; c < MSPLIT; c++) {
            float v2 = candv[base + c * NOBJ];
            int   i2 = candi[base + c * NOBJ];
            if (v2 > v || (v2 == v && i2 < ix)) { v = v2; ix = i2; }
        }
        bpi_g[b * NOBJ + j] = ix;
    }
}

// ---------------------------------------------------------------- k_match_c
// Conf/loc phase, 16x parallel, 256-thread blocks. Override semantics:
// reference scatters idx=j ascending (later j wins), ov=2.0 -> conf=label.
__global__ __launch_bounds__(256) void k_match_c(
    const float* __restrict__ loc_data,
    const float* __restrict__ gt_boxes,
    const int*   __restrict__ gt_labels,
    const float* __restrict__ priors,
    const float* __restrict__ ov_g,
    const unsigned char* __restrict__ idx_g,
    const int*   __restrict__ bpi_g,
    int*   __restrict__ conf_t,
    float* __restrict__ ll_part,           // [B*MSPLIT]
    int*   __restrict__ np_part)           // [B*MSPLIT]
{
    __shared__ float bx0[NOBJ], by0[NOBJ], bx1[NOBJ], by1[NOBJ];
    __shared__ int   blab[NOBJ], bpi_s[NOBJ];
    __shared__ float red_f[4];
    __shared__ int   red_i[4];

    const int b    = blockIdx.y;
    const int blk  = blockIdx.x;
    const int tid  = threadIdx.x;
    const int lane = tid & 63;
    const int wave = tid >> 6;
    const int p0   = blk * SL;
    const int pend = min(p0 + SL, NPRIOR);

    if (tid < NOBJ) {
        float4 g = ((const float4*)gt_boxes)[(size_t)b * NOBJ + tid];
        bx0[tid] = g.x * (1.0f / IMG); by0[tid] = g.y * (1.0f / IMG);
        bx1[tid] = g.z * (1.0f / IMG); by1[tid] = g.w * (1.0f / IMG);
        blab[tid]  = gt_labels[b * NOBJ + tid];
        bpi_s[tid] = bpi_g[b * NOBJ + tid];
    }
    __syncthreads();

    int np_local = 0;
    float ll_local = 0.0f;
    for (int p = p0 + tid; p < pend; p += 256) {
        float ov = ov_g[(size_t)b * NPRIOR + p];
        int ti = (int)idx_g[(size_t)b * NPRIOR + p];
        int oj = -1;
#pragma unroll
        for (int j = 0; j < NOBJ; j++)
            if (bpi_s[j] == p) oj = j;       // last j wins (in-order scatter)
        int conf;
        if (oj >= 0) { ti = oj; conf = blab[oj]; }   // ov=2.0 >= 0.5
        else         { conf = (ov < 0.5f) ? 0 : blab[ti]; }
        conf_t[(size_t)b * NPRIOR + p] = conf;
        if (conf > 0) {
            np_local++;
            float4 pr = ((const float4*)priors)[p];
            float cx = pr.x, cy = pr.y, w = pr.z, h = pr.w;
            float mx0 = bx0[ti], my0 = by0[ti], mx1 = bx1[ti], my1 = by1[ti];
            float g0 = ((mx0 + mx1) * 0.5f - cx) / (0.1f * w);
            float g1 = ((my0 + my1) * 0.5f - cy) / (0.1f * h);
            float g2 = logf((mx1 - mx0) / w) * 5.0f;
            float g3 = logf((my1 - my0) / h) * 5.0f;
            float4 lv = ((const float4*)loc_data)[(size_t)b * NPRIOR + p];
            float d0 = lv.x - g0, d1 = lv.y - g1, d2 = lv.z - g2, d3 = lv.w - g3;
            float a0 = fabsf(d0), a1 = fabsf(d1), a2 = fabsf(d2), a3 = fabsf(d3);
            ll_local += (a0 < 1.f ? 0.5f * d0 * d0 : a0 - 0.5f)
                      + (a1 < 1.f ? 0.5f * d1 * d1 : a1 - 0.5f)
                      + (a2 < 1.f ? 0.5f * d2 * d2 : a2 - 0.5f)
                      + (a3 < 1.f ? 0.5f * d3 * d3 : a3 - 0.5f);
        }
    }
    for (int off = 32; off; off >>= 1) {
        ll_local += __shfl_xor(ll_local, off);
        np_local += __shfl_xor(np_local, off);
    }
    if (lane == 0) { red_f[wave] = ll_local; red_i[wave] = np_local; }
    __syncthreads();
    if (tid == 0) {
        float ll = red_f[0] + red_f[1] + red_f[2] + red_f[3];
        int   np = red_i[0] + red_i[1] + red_i[2] + red_i[3];
        ll_part[b * MSPLIT + blk] = ll;
        np_part[b * MSPLIT + blk] = np;
    }
}

// ---------------------------------------------------------------- k_ce
// One-wave persistent blocks, zero barriers, depth-2 register pipeline.

#define CE_ISSUE(gg, R0, R1, R2, NF)                                           \
    {   int b_ = (gg) / GPB, ci_ = (gg) - b_ * GPB;                            \
        int p0_ = ci_ * 8;                                                     \
        int rows_ = min(8, NPRIOR - p0_);                                      \
        NF = (rows_ * NC) >> 2;                                                \
        const float4* s_ = (const float4*)(conf_data + ((size_t)b_ * NPRIOR + p0_) * NC); \
        R0 = s_[tid];                                                          \
        if (tid + 64  < NF) R1 = s_[tid + 64];                                 \
        if (tid + 128 < NF) R2 = s_[tid + 128]; }

#define CT_LOAD(gg)                                                            \
    ( conf_t[(size_t)((gg) / GPB) * NPRIOR + ((gg) - ((gg) / GPB) * GPB) * 8 + (tid >> 3)] )

#define CE_WRITE(BUF, R0, R1, R2, NF)                                          \
    {   float4* d_ = (float4*)sbuf[BUF];                                       \
        d_[tid] = R0;                                                          \
        if (tid + 64  < NF) d_[tid + 64]  = R1;                                \
        if (tid + 128 < NF) d_[tid + 128] = R2; }

#define CE_COMPUTE(gg, BUF, TG)                                                \
    {   int b_ = (gg) / GPB, ci_ = (gg) - b_ * GPB;                            \
        int p0_ = ci_ * 8;                                                     \
        int rows_ = min(8, NPRIOR - p0_);                                      \
        int rr_ = tid >> 3, q_ = tid & 7;                                      \
        if (rr_ < rows_) {                                                     \
            const float* row_ = sbuf[BUF] + rr_ * NC;                          \
            float s_ = 0.0f;                                                   \
            _Pragma("unroll")                                                  \
            for (int i_ = q_; i_ < NC; i_ += 8) s_ += __expf(row_[i_]);        \
            s_ += __shfl_xor(s_, 1);                                           \
            s_ += __shfl_xor(s_, 2);                                           \
            s_ += __shfl_xor(s_, 4);                                           \
            if (q_ == 0) {                                                     \
                size_t o_ = (size_t)b_ * NPRIOR + p0_ + rr_;                   \
                int tgt_ = TG;                                                 \
                float ce_ = __logf(s_) - row_[tgt_];                           \
                if (tgt_ > 0) { pos_acc += ce_; mine[o_] = 0.0f; }             \
                else          { mine[o_] = fmaxf(ce_, 0.0f); }                 \
            } } }

__global__ __launch_bounds__(64) void k_ce(
    const float* __restrict__ conf_data,
    const int*   __restrict__ conf_t,
    float* __restrict__ mine,
    float* __restrict__ lc_part)
{
    __shared__ float sbuf[2][8 * NC];
    const int tid = threadIdx.x;
    const int G = CE_GRID;

    float4 a0, a1, a2, b0, b1, b2;
    int nfA = 0, nfB = 0;
    float pos_acc = 0.0f;

    int g = blockIdx.x;
    CE_ISSUE(g, a0, a1, a2, nfA);
    int tcur = CT_LOAD(g);
    if (g + G < NGROUP) CE_ISSUE(g + G, b0, b1, b2, nfB);
    CE_WRITE(0, a0, a1, a2, nfA);

    for (; g < NGROUP; g += 2 * G) {
        int tnext = (g + G < NGROUP) ? CT_LOAD(g + G) : 0;
        if (g + 2 * G < NGROUP) CE_ISSUE(g + 2 * G, a0, a1, a2, nfA);
        CE_COMPUTE(g, 0, tcur);
        if (g + G < NGROUP) {
            CE_WRITE(1, b0, b1, b2, nfB);
            int tn2 = (g + 2 * G < NGROUP) ? CT_LOAD(g + 2 * G) : 0;
            if (g + 3 * G < NGROUP) CE_ISSUE(g + 3 * G, b0, b1, b2, nfB);
            CE_COMPUTE(g + G, 1, tnext);
            if (g + 2 * G < NGROUP) CE_WRITE(0, a0, a1, a2, nfA);
            tcur = tn2;
        }
    }

    for (int off = 32; off; off >>= 1) pos_acc += __shfl_xor(pos_acc, off);
    if (tid == 0) lc_part[blockIdx.x] = pos_acc;
}

// ---------------------------------------------------------------- k_hist
__global__ __launch_bounds__(256) void k_hist(
    const float* __restrict__ mine,
    int*   __restrict__ ghc,          // [B][HB][GBINS]
    float* __restrict__ gsc)          // [B][HB][GBINS]
{
    __shared__ int   lh[GBINS];
    __shared__ float ls[GBINS];

    const int b  = blockIdx.y;
    const int ci = blockIdx.x;
    const int tid = threadIdx.x;
    const int i0 = ci * HCHUNK;
    const int iend = min(i0 + HCHUNK, NPRIOR);

#pragma unroll
    for (int j = 0; j < GBINS / 256; j++) {
        lh[tid + j * 256] = 0;
        ls[tid + j * 256] = 0.0f;
    }
    __syncthreads();

    for (int i = i0 + tid; i < iend; i += 256) {
        float v = mine[(size_t)b * NPRIOR + i];
        int bin = min((int)(v * 128.0f), GBINS - 1);
        atomicAdd(&lh[bin], 1);
        atomicAdd(&ls[bin], v);
    }
    __syncthreads();

    const size_t base = ((size_t)b * HB + ci) * GBINS;
#pragma unroll
    for (int j = 0; j < GBINS / 256; j++) {
        int bin = tid + j * 256;
        ghc[base + bin] = lh[bin];
        gsc[base + bin] = ls[bin];
    }
}

// ---------------------------------------------------------------- k_sel
__global__ __launch_bounds__(1024) void k_sel(
    const int*   __restrict__ ghc,
    const float* __restrict__ gsc,
    const int*   __restrict__ np_part,
    float* __restrict__ lc2)
{
    __shared__ int   wtot[16];
    __shared__ int   s_B0, s_r;
    __shared__ float red_f[16];

    const int b = blockIdx.x;
    const int tid = threadIdx.x;
    const int lane = tid & 63;
    const int wave = tid >> 6;

    int   c0 = 0, c1 = 0;
    float m0 = 0.0f, m1 = 0.0f;
    const size_t base = (size_t)b * HB * GBINS;
#pragma unroll
    for (int c = 0; c < HB; c++) {
        c0 += ghc[base + (size_t)c * GBINS + 2 * tid];
        c1 += ghc[base + (size_t)c * GBINS + 2 * tid + 1];
        m0 += gsc[base + (size_t)c * GBINS + 2 * tid];
        m1 += gsc[base + (size_t)c * GBINS + 2 * tid + 1];
    }

    int np = 0;
#pragma unroll
    for (int c = 0; c < MSPLIT; c++) np += np_part[b * MSPLIT + c];
    const int kk = min(max(3 * np, 1), NPRIOR - 1);

    const int ps = c0 + c1;
    int incl = ps;
#pragma unroll
    for (int off = 1; off < 64; off <<= 1) {
        int t = __shfl_down(incl, off);
        incl += (lane + off < 64) ? t : 0;
    }
    if (lane == 0) wtot[wave] = incl;
    __syncthreads();
    int hi = 0;
#pragma unroll
    for (int w = 0; w < 16; w++) if (w > wave) hi += wtot[w];
    const int suf = (incl - ps) + hi;
    if (suf < kk && kk <= suf + c1)          { s_B0 = 2 * tid + 1; s_r = kk - suf; }
    const int suf1 = suf + c1;
    if (suf1 < kk && kk <= suf1 + c0)        { s_B0 = 2 * tid;     s_r = kk - suf1; }
    __syncthreads();

    const int B0 = s_B0;
    const int r  = s_r;

    float sg = 0.0f;
    if (2 * tid     > B0) sg += m0;
    if (2 * tid + 1 > B0) sg += m1;
    if      (2 * tid     == B0) sg += (float)r * (m0 / (float)c0);
    else if (2 * tid + 1 == B0) sg += (float)r * (m1 / (float)c1);

    for (int off = 32; off; off >>= 1) sg += __shfl_xor(sg, off);
    if (lane == 0) red_f[wave] = sg;
    __syncthreads();
    if (tid == 0) {
        float s = 0.0f;
#pragma unroll
        for (int w = 0; w < 16; w++) s += red_f[w];
        lc2[b] = s;
    }
}

// ---------------------------------------------------------------- k_final
__global__ __launch_bounds__(1024) void k_final(
    const float* __restrict__ lc_part, const float* __restrict__ lc2,
    const float* __restrict__ ll_part, const int* __restrict__ np_part,
    float* __restrict__ out)
{
    __shared__ float rf[16][2];
    __shared__ int   rn[16];
    const int tid = threadIdx.x;
    float lc = 0.0f;
    for (int i = tid; i < CE_GRID; i += 1024) lc += lc_part[i];
    float ll = 0.0f; int np = 0;
    if (tid < BATCH) lc += lc2[tid];
    if (tid < BATCH * MSPLIT) { ll = ll_part[tid]; np = np_part[tid]; }
    for (int off = 32; off; off >>= 1) {
        lc += __shfl_xor(lc, off);
        ll += __shfl_xor(ll, off);
        np += __shfl_xor(np, off);
    }
    const int lane = tid & 63, wave = tid >> 6;
    if (lane == 0) { rf[wave][0] = lc; rf[wave][1] = ll; rn[wave] = np; }
    __syncthreads();
    if (tid == 0) {
        float lcT = 0.0f, llT = 0.0f; int npT = 0;
        for (int w = 0; w < 16; w++) { lcT += rf[w][0]; llT += rf[w][1]; npT += rn[w]; }
        float N = fmaxf((float)npT, 1.0f);
        out[0] = llT / N;
        out[1] = lcT / N;
    }
}

// ---------------------------------------------------------------- launch
extern "C" void kernel_launch(void* const* d_in, const int* in_sizes, int n_in,
                              void* d_out, int out_size, void* d_ws, size_t ws_size,
                              hipStream_t stream)
{
    const float* loc_data  = (const float*)d_in[0];
    const float* conf_data = (const float*)d_in[1];
    const float* gt_boxes  = (const float*)d_in[2];
    const int*   gt_labels = (const int*)d_in[3];
    const float* priors    = (const float*)d_in[4];
    float* out = (float*)d_out;

    char* ws = (char*)d_ws;
    float* ll_part  = (float*)(ws + 0);                          // 1024 floats
    int*   np_part  = (int*)(ws + 4096);                         // 1024 ints
    float* lc2      = (float*)(ws + 8192);                       // 64 floats
    float* lc_part  = (float*)(ws + 12288);                      // 6144 floats
    int*   conf_t   = (int*)(ws + 65536);                        // 2.24 MB
    float* mine     = (float*)(ws + 65536 + 2235392);            // 2.24 MB
    float* ov_g     = (float*)(ws + 4536320);                    // 2.24 MB
    unsigned char* idx_g = (unsigned char*)(ws + 6771712);       // 0.56 MB
    float* candv    = (float*)(ws + 7340032);                    // 64 KB
    int*   candi    = (int*)(ws + 7405568);                      // 64 KB
    int*   bpi_g    = (int*)(ws + 7471104);                      // 4 KB
    int*   ghc      = (int*)(ws + 16777216);                     // 8 MB
    float* gsc      = (float*)(ws + 25165824);                   // 8 MB

    hipLaunchKernelGGL(k_match_a, dim3(MSPLIT, BATCH), dim3(256), 0, stream,
                       gt_boxes, priors, ov_g, idx_g, candv, candi);
    hipLaunchKernelGGL(k_bpi, dim3(BATCH), dim3(64), 0, stream,
                       candv, candi, bpi_g);
    hipLaunchKernelGGL(k_match_c, dim3(MSPLIT, BATCH), dim3(256), 0, stream,
                       loc_data, gt_boxes, gt_labels, priors, ov_g, idx_g,
                       bpi_g, conf_t, ll_part, np_part);
    hipLaunchKernelGGL(k_ce, dim3(CE_GRID), dim3(64), 0, stream,
                       conf_data, conf_t, mine, lc_part);
    hipLaunchKernelGGL(k_hist, dim3(HB, BATCH), dim3(256), 0, stream,
                       mine, ghc, gsc);
    hipLaunchKernelGGL(k_sel, dim3(BATCH), dim3(1024), 0, stream,
                       ghc, gsc, np_part, lc2);
    hipLaunchKernelGGL(k_final, dim3(1), dim3(1024), 0, stream,
                       lc_part, lc2, ll_part, np_part, out);
}